// Round 7
// baseline (58.765 us; speedup 1.0000x reference)
//
#include <hip/hip_runtime.h>
#include <math.h>

// WindAdjacency: A[b,i,j] = mask*exp(align - D/R)*speed, row-normalized.
// B=8, N=2048. Round-7: round-6 kernel with LINEAR block mapping (A/B test).
//   p = b*2048 + i  ->  XCD = p%8 = i%8 (2048 == 0 mod 8):
//   - writes: consecutive blocks on an XCD write rows 8 apart in the SAME
//     batch plane (32KB stride, near-sequential) -- matches the 6.8TB/s
//     fill kernels' access shape. (Round-6 wrote 16MB apart across planes.)
//   - reads: each XCD only touches rows i%8==x (4.2MB, ~L2-resident; L3
//     backstops all 8x batch re-reads -- D/Theta total 33.6MB << 256MB L3)

#define NN 2048
#define BB 8

typedef float f32x4 __attribute__((ext_vector_type(4)));

__global__ __launch_bounds__(256) void wind_adj_kernel(
    const float* __restrict__ wind_feats,  // [B,N,2]
    const float* __restrict__ D,           // [N,N]
    const float* __restrict__ Theta,       // [N,N]
    float* __restrict__ out)               // [B,N,N]
{
    constexpr float PI_F     = 3.14159265358979323846f;
    constexpr float TWO_PI_F = 6.28318530717958647692f;
    constexpr float CONE_F   = 0.78539816339744830962f;  // f32(pi/4)
    constexpr float R_INV    = 1.0f / 150.0f;
    constexpr float EPS      = 1e-8f;

    // linear mapping: one block per (b,i), i fastest
    const int p = blockIdx.x;
    const int b = p >> 11;
    const int i = p & (NN - 1);

    const int tid = threadIdx.x;  // 0..255, two float4 (8 j's) per thread

    const f32x4* __restrict__ Drow = reinterpret_cast<const f32x4*>(D     + (size_t)i * NN);
    const f32x4* __restrict__ Trow = reinterpret_cast<const f32x4*>(Theta + (size_t)i * NN);
    const f32x4 d4a = Drow[tid];
    const f32x4 t4a = Trow[tid];
    const f32x4 d4b = Drow[256 + tid];
    const f32x4 t4b = Trow[256 + tid];

    const float speed = wind_feats[((size_t)b * NN + i) * 2 + 0];
    float wind_to     = wind_feats[((size_t)b * NN + i) * 2 + 1] + PI_F;
    if (wind_to >= TWO_PI_F) wind_to -= TWO_PI_F;   // dir in [0,1): mod is identity

    float vals[2][4];
    float psum = 0.0f;

    #pragma unroll
    for (int h = 0; h < 2; ++h) {
        const f32x4 d4 = h ? d4b : d4a;
        const f32x4 t4 = h ? t4b : t4a;
        #pragma unroll
        for (int e = 0; e < 4; ++e) {
            const int j = (h * 256 + tid) * 4 + e;
            // exact f32 replication of ref: ang = ((Theta - wind_to) + pi) mod 2pi - pi
            float t = t4[e] - wind_to + PI_F;        // in (-1, 2pi]
            t = (t < 0.0f) ? (t + TWO_PI_F) : t;     // == np.mod for this range
            float ang = t - PI_F;
            float align = fmaxf(__cosf(ang), 0.0f);
            float v = __expf(__builtin_fmaf(d4[e], -R_INV, align));  // exp(align - D/R)
            v = (fabsf(ang) <= CONE_F) ? v : 0.0f;   // cone mask, bit-exact compare
            v = (j == i) ? 0.0f : v;                 // no self loop
            vals[h][e] = v;
            psum += v;
        }
    }

    // block reduction: wave butterfly then LDS across the 4 waves
    float s = psum;
    #pragma unroll
    for (int off = 32; off > 0; off >>= 1) s += __shfl_down(s, off);
    __shared__ float wsum[4];
    const int lane = tid & 63, wid = tid >> 6;
    if (lane == 0) wsum[wid] = s;
    __syncthreads();
    const float total = wsum[0] + wsum[1] + wsum[2] + wsum[3];

    // A = (v*speed) / (sum(v)*speed + eps)
    const float scale = speed / __builtin_fmaf(total, speed, EPS);

    f32x4* __restrict__ Orow = reinterpret_cast<f32x4*>(out + ((size_t)b * NN + i) * NN);
    #pragma unroll
    for (int h = 0; h < 2; ++h) {
        f32x4 o;
        o[0] = vals[h][0] * scale;
        o[1] = vals[h][1] * scale;
        o[2] = vals[h][2] * scale;
        o[3] = vals[h][3] * scale;
        Orow[h * 256 + tid] = o;
    }
}

extern "C" void kernel_launch(void* const* d_in, const int* in_sizes, int n_in,
                              void* d_out, int out_size, void* d_ws, size_t ws_size,
                              hipStream_t stream) {
    const float* wind_feats = (const float*)d_in[0];  // [8,2048,2]
    const float* D_ij       = (const float*)d_in[1];  // [2048,2048]
    const float* Theta_ij   = (const float*)d_in[2];  // [2048,2048]
    float* out = (float*)d_out;                       // [8,2048,2048]

    dim3 grid(BB * NN);   // linear: p = b*2048 + i
    dim3 block(256);
    wind_adj_kernel<<<grid, block, 0, stream>>>(wind_feats, D_ij, Theta_ij, out);
}

// Round 8
// 33.601 us; speedup vs baseline: 1.7489x; 1.7489x over previous
//
#include <hip/hip_runtime.h>
#include <math.h>

// WindAdjacency: A[b,i,j] = mask*exp(align - D/R)*speed, row-normalized.
// B=8, N=2048. Round-8: one block (512 thr = 8 waves) per row i; wave w owns
// batch b=w for the WHOLE row (32 elems/lane). Properties:
//   - all 8 waves read the same 16KB D/Theta row -> L1-resident (32KB/CU);
//     each row fetched from HBM exactly once (keeps round-6's key win)
//   - waves fully independent: wave-local shfl_xor reduction, NO
//     __syncthreads, NO LDS -> no load/store convoy
//   - per-wave stores: contiguous 8KB row; each store instr = dense 1KB
//   - vals[8][4]=32 VGPR + chunk staging -> ~64 VGPR, no occupancy cliff

#define NN 2048
#define BB 8

typedef float f32x4 __attribute__((ext_vector_type(4)));

__global__ __launch_bounds__(512) void wind_adj_kernel(
    const float* __restrict__ wind_feats,  // [B,N,2]
    const float* __restrict__ D,           // [N,N]
    const float* __restrict__ Theta,       // [N,N]
    float* __restrict__ out)               // [B,N,N]
{
    constexpr float PI_F     = 3.14159265358979323846f;
    constexpr float TWO_PI_F = 6.28318530717958647692f;
    constexpr float CONE_F   = 0.78539816339744830962f;  // f32(pi/4)
    constexpr float R_INV    = 1.0f / 150.0f;
    constexpr float EPS      = 1e-8f;

    const int i    = blockIdx.x;          // row
    const int lane = threadIdx.x & 63;
    const int b    = threadIdx.x >> 6;    // wave index = batch

    const float speed = wind_feats[((size_t)b * NN + i) * 2 + 0];
    float wind_to     = wind_feats[((size_t)b * NN + i) * 2 + 1] + PI_F;
    if (wind_to >= TWO_PI_F) wind_to -= TWO_PI_F;   // dir in [0,1): mod is identity

    const f32x4* __restrict__ Drow = reinterpret_cast<const f32x4*>(D     + (size_t)i * NN);
    const f32x4* __restrict__ Trow = reinterpret_cast<const f32x4*>(Theta + (size_t)i * NN);

    float vals[8][4];    // [chunk][e] -> 32 VGPRs, static after unroll
    float psum = 0.0f;

    #pragma unroll
    for (int c = 0; c < 8; ++c) {
        const int f4 = c * 64 + lane;     // dense 1KB/wave per load
        const f32x4 d4 = Drow[f4];
        const f32x4 t4 = Trow[f4];
        #pragma unroll
        for (int e = 0; e < 4; ++e) {
            const int j = f4 * 4 + e;
            // exact f32 replication of ref: ang = ((Theta - wind_to) + pi) mod 2pi - pi
            float t = t4[e] - wind_to + PI_F;        // in (-1, 2pi]
            t = (t < 0.0f) ? (t + TWO_PI_F) : t;     // == np.mod for this range
            float ang = t - PI_F;
            float align = fmaxf(__cosf(ang), 0.0f);
            float v = __expf(__builtin_fmaf(d4[e], -R_INV, align));  // exp(align - D/R)
            v = (fabsf(ang) <= CONE_F) ? v : 0.0f;   // cone mask, bit-exact compare
            v = (j == i) ? 0.0f : v;                 // no self loop
            vals[c][e] = v;
            psum += v;
        }
    }

    // wave-local butterfly reduction: result in all 64 lanes, no LDS/barrier
    #pragma unroll
    for (int off = 1; off < 64; off <<= 1) psum += __shfl_xor(psum, off);

    // A = (v*speed) / (sum(v)*speed + eps)
    const float scale = speed / __builtin_fmaf(psum, speed, EPS);

    f32x4* __restrict__ Orow = reinterpret_cast<f32x4*>(out + ((size_t)b * NN + i) * NN);
    #pragma unroll
    for (int c = 0; c < 8; ++c) {
        f32x4 o;
        o[0] = vals[c][0] * scale;
        o[1] = vals[c][1] * scale;
        o[2] = vals[c][2] * scale;
        o[3] = vals[c][3] * scale;
        Orow[c * 64 + lane] = o;
    }
}

extern "C" void kernel_launch(void* const* d_in, const int* in_sizes, int n_in,
                              void* d_out, int out_size, void* d_ws, size_t ws_size,
                              hipStream_t stream) {
    const float* wind_feats = (const float*)d_in[0];  // [8,2048,2]
    const float* D_ij       = (const float*)d_in[1];  // [2048,2048]
    const float* Theta_ij   = (const float*)d_in[2];  // [2048,2048]
    float* out = (float*)d_out;                       // [8,2048,2048]

    dim3 grid(NN);        // one block per row; 8 waves = 8 batches, independent
    dim3 block(512);
    wind_adj_kernel<<<grid, block, 0, stream>>>(wind_feats, D_ij, Theta_ij, out);
}